// Round 7
// baseline (451.919 us; speedup 1.0000x reference)
//
#include <hip/hip_runtime.h>
#include <hip/hip_bf16.h>

#define N_IN      256
#define N_OUTC    128
#define RPS       64       // rows per superbin
#define RPS_SHIFT 6
#define NSB_MAX   1024
#define TILE      4096     // edges per build block
#define EPT       16       // edges per thread in build
#define SPILL_CAP 8192

typedef __attribute__((ext_vector_type(8))) short bf16x8;
typedef __attribute__((ext_vector_type(4))) float f32x4;
typedef unsigned short ushort_t;
typedef unsigned int uint_t;

__device__ inline unsigned short f2bf(float f) {
    unsigned u = __float_as_uint(f);
    unsigned r = u + 0x7fffu + ((u >> 16) & 1u);
    return (unsigned short)(r >> 16);
}
__device__ inline float bf_lo(uint_t g) { return __uint_as_float(g << 16); }
__device__ inline float bf_hi(uint_t g) { return __uint_as_float(g & 0xFFFF0000u); }

// ---------------- W fp32 [128,256] -> bf16 ----------------
__global__ void cvtW_kernel(const float* __restrict__ W, ushort_t* __restrict__ wb, int n) {
    int i = blockIdx.x * blockDim.x + threadIdx.x;
    if (i < n) wb[i] = f2bf(W[i]);
}

// ---------------- buildA: LDS-ranked superbin binning (round-0 verbatim, standalone) ----------------
__global__ __launch_bounds__(256) void build_kernel(
        const int* __restrict__ rows, const int* __restrict__ cols,
        const float* __restrict__ vals, int E,
        int* __restrict__ sbCount, int2* __restrict__ sbList, int sbCap, int nsb,
        int* __restrict__ spillCnt, int4* __restrict__ spill) {
    __shared__ int cur[NSB_MAX];
    __shared__ int gbase[NSB_MAX];
    const int tid = threadIdx.x;
    const int base = blockIdx.x * TILE;
    for (int i = tid; i < nsb; i += 256) cur[i] = 0;
    __syncthreads();

    int ex[EPT], evb[EPT], esb[EPT], erk[EPT];
    #pragma unroll
    for (int k = 0; k < EPT; k++) {
        int e = base + tid + k * 256;
        if (e < E) {
            int r = rows[e], c = cols[e];
            evb[k] = __float_as_int(vals[e]);
            esb[k] = r >> RPS_SHIFT;
            ex[k]  = c | ((r & (RPS - 1)) << 17);
            erk[k] = atomicAdd(&cur[esb[k]], 1);
        } else esb[k] = -1;
    }
    __syncthreads();
    for (int i = tid; i < nsb; i += 256)
        gbase[i] = cur[i] ? atomicAdd(&sbCount[i], cur[i]) : 0;
    __syncthreads();

    #pragma unroll
    for (int k = 0; k < EPT; k++) {
        if (esb[k] < 0) continue;
        int pos = gbase[esb[k]] + erk[k];
        if (pos < sbCap) {
            sbList[(size_t)esb[k] * sbCap + pos] = make_int2(ex[k], evb[k]);
        } else {
            int sp = atomicAdd(spillCnt, 1);
            if (sp < SPILL_CAP)
                spill[sp] = make_int4((esb[k] << RPS_SHIFT) + (int)(((uint_t)ex[k]) >> 17),
                                      ex[k] & 0x1FFFF, evb[k], 0);
        }
    }
}

// ---------------- gemm: h = x @ W^T + b, bf16 out (round-0 body, no LDS) ----------------
__global__ __launch_bounds__(256) void gemm_only_kernel(const float* __restrict__ x,
                                                        const ushort_t* __restrict__ wb,
                                                        const float* __restrict__ b,
                                                        ushort_t* __restrict__ h16) {
    const int tid  = threadIdx.x;
    const int wave = tid >> 6;
    const int lane = tid & 63;
    const int quad = lane >> 4;
    const int l16  = lane & 15;
    const int m0   = blockIdx.x * 16;
    const int colbase = wave * 32;
    f32x4 acc0 = {0.f, 0.f, 0.f, 0.f};
    f32x4 acc1 = {0.f, 0.f, 0.f, 0.f};
    const float* xrow = x + (size_t)(m0 + l16) * N_IN + quad * 8;   // A: m=lane&15, k=quad*8+j
    const ushort_t* w0 = wb + (size_t)(colbase + l16) * N_IN + quad * 8;
    const ushort_t* w1 = w0 + 16 * N_IN;
    #pragma unroll
    for (int kb = 0; kb < N_IN; kb += 32) {
        float4 a0 = *(const float4*)(xrow + kb);
        float4 a1 = *(const float4*)(xrow + kb + 4);
        union { bf16x8 v; __hip_bfloat162 h2[4]; } u;
        u.h2[0] = __float22bfloat162_rn(make_float2(a0.x, a0.y));
        u.h2[1] = __float22bfloat162_rn(make_float2(a0.z, a0.w));
        u.h2[2] = __float22bfloat162_rn(make_float2(a1.x, a1.y));
        u.h2[3] = __float22bfloat162_rn(make_float2(a1.z, a1.w));
        bf16x8 bf0 = *(const bf16x8*)(w0 + kb);
        bf16x8 bf1 = *(const bf16x8*)(w1 + kb);
        acc0 = __builtin_amdgcn_mfma_f32_16x16x32_bf16(u.v, bf0, acc0, 0, 0, 0);
        acc1 = __builtin_amdgcn_mfma_f32_16x16x32_bf16(u.v, bf1, acc1, 0, 0, 0);
    }
    const int c0 = colbase + l16;
    const int c1 = c0 + 16;
    const float bv0 = b[c0];
    const float bv1 = b[c1];
    ushort_t* hp = h16 + (size_t)(m0 + quad * 4) * N_OUTC;
    #pragma unroll
    for (int r = 0; r < 4; r++) {
        hp[(size_t)r * N_OUTC + c0] = f2bf(acc0[r] + bv0);
        hp[(size_t)r * N_OUTC + c1] = f2bf(acc1[r] + bv1);
    }
}

// ---------------- exclusive scan of clamped superbin totals (1 block, 1024 thr) ----------------
__global__ __launch_bounds__(1024) void sbscan_kernel(const int* __restrict__ sbCount, int sbCap,
                                                      int* __restrict__ sbBase, int nsb) {
    __shared__ int a[NSB_MAX], bsh[NSB_MAX];
    int tid = threadIdx.x;
    int v = 0;
    if (tid < nsb) { v = sbCount[tid]; if (v > sbCap) v = sbCap; }
    a[tid] = v; __syncthreads();
    int* src = a; int* dst = bsh;
    for (int off = 1; off < 1024; off <<= 1) {
        dst[tid] = src[tid] + ((tid >= off) ? src[tid - off] : 0);
        __syncthreads();
        int* t = src; src = dst; dst = t;
    }
    if (tid < nsb) sbBase[tid] = tid ? src[tid - 1] : 0;
}

// ---------------- sort: superbin list -> CSR; now 1024 thr/block (4x waves for latency) ----------------
__global__ __launch_bounds__(1024) void sort_kernel(const int* __restrict__ sbCount,
                                                    const int* __restrict__ sbBase,
                                                    const int2* __restrict__ sbList, int sbCap,
                                                    int2* __restrict__ csr,
                                                    int* __restrict__ rowStart, int* __restrict__ rowCnt,
                                                    int Ndst) {
    __shared__ int hist[RPS];
    __shared__ int scanA[RPS];
    __shared__ int curx[RPS];
    const int sb  = blockIdx.x;
    const int tid = threadIdx.x;
    int len = sbCount[sb]; if (len > sbCap) len = sbCap;
    const int base = sbBase[sb];
    const int2* lp = sbList + (size_t)sb * sbCap;

    if (tid < RPS) hist[tid] = 0;
    __syncthreads();

    // phase 1: histogram (4-deep prefetch, 1024-thread stride)
    int i = tid;
    for (; i + 3072 < len; i += 4096) {
        int x0 = lp[i].x, x1 = lp[i + 1024].x, x2 = lp[i + 2048].x, x3 = lp[i + 3072].x;
        atomicAdd(&hist[((uint_t)x0) >> 17], 1);
        atomicAdd(&hist[((uint_t)x1) >> 17], 1);
        atomicAdd(&hist[((uint_t)x2) >> 17], 1);
        atomicAdd(&hist[((uint_t)x3) >> 17], 1);
    }
    for (; i < len; i += 1024) atomicAdd(&hist[((uint_t)lp[i].x) >> 17], 1);
    __syncthreads();

    // phase 2: inclusive scan over 64 rows (predicated Hillis-Steele)
    if (tid < RPS) scanA[tid] = hist[tid];
    __syncthreads();
    for (int off = 1; off < RPS; off <<= 1) {
        int t = 0;
        if (tid < RPS) t = scanA[tid] + ((tid >= off) ? scanA[tid - off] : 0);
        __syncthreads();
        if (tid < RPS) scanA[tid] = t;
        __syncthreads();
    }
    if (tid < RPS) {
        int excl = tid ? scanA[tid - 1] : 0;
        curx[tid] = excl;
        int r = sb * RPS + tid;
        if (r < Ndst) { rowStart[r] = base + excl; rowCnt[r] = hist[tid]; }
    }
    __syncthreads();

    // phase 3: scatter (4-deep prefetch); writes stay within this sb's 32KB CSR span (L2-resident)
    i = tid;
    for (; i + 3072 < len; i += 4096) {
        int2 e0 = lp[i], e1 = lp[i + 1024], e2 = lp[i + 2048], e3 = lp[i + 3072];
        int p0 = atomicAdd(&curx[((uint_t)e0.x) >> 17], 1);
        int p1 = atomicAdd(&curx[((uint_t)e1.x) >> 17], 1);
        int p2 = atomicAdd(&curx[((uint_t)e2.x) >> 17], 1);
        int p3 = atomicAdd(&curx[((uint_t)e3.x) >> 17], 1);
        csr[(size_t)base + p0] = make_int2(e0.x & 0x1FFFF, e0.y);
        csr[(size_t)base + p1] = make_int2(e1.x & 0x1FFFF, e1.y);
        csr[(size_t)base + p2] = make_int2(e2.x & 0x1FFFF, e2.y);
        csr[(size_t)base + p3] = make_int2(e3.x & 0x1FFFF, e3.y);
    }
    for (; i < len; i += 1024) {
        int2 e = lp[i];
        int pos = atomicAdd(&curx[((uint_t)e.x) >> 17], 1);
        csr[(size_t)base + pos] = make_int2(e.x & 0x1FFFF, e.y);
    }
}

// ---------------- SpMM: wave per dst row, coalesced edge loads + shfl broadcast ----------------
__global__ __launch_bounds__(256) void spmm_concat_kernel(const ushort_t* __restrict__ h16,
                                                          const int* __restrict__ rowStart,
                                                          const int* __restrict__ rowCnt,
                                                          const int2* __restrict__ csr,
                                                          const int* __restrict__ prev,
                                                          float* __restrict__ out, int Ndst) {
    int r = blockIdx.x * 4 + (threadIdx.x >> 6);
    if (r >= Ndst) return;
    const int lane = threadIdx.x & 63;
    const int cnt = rowCnt[r];
    const int2* bk = csr + rowStart[r];

    float2 acc = {0.f, 0.f};
    for (int bse = 0; bse < cnt; bse += 64) {
        int idx = bse + lane;
        int2 my = make_int2(0, 0);             // pad: v=0 -> zero contribution, c=0 safe
        if (idx < cnt) my = bk[idx];
        int m = cnt - bse; if (m > 64) m = 64;
        int mg = (m + 7) & ~7;
        for (int j = 0; j < mg; j += 8) {
            int c0 = __shfl(my.x, j + 0), c1 = __shfl(my.x, j + 1);
            int c2 = __shfl(my.x, j + 2), c3 = __shfl(my.x, j + 3);
            int c4 = __shfl(my.x, j + 4), c5 = __shfl(my.x, j + 5);
            int c6 = __shfl(my.x, j + 6), c7 = __shfl(my.x, j + 7);
            uint_t g0 = *(const uint_t*)(h16 + (size_t)c0 * N_OUTC + 2 * lane);
            uint_t g1 = *(const uint_t*)(h16 + (size_t)c1 * N_OUTC + 2 * lane);
            uint_t g2 = *(const uint_t*)(h16 + (size_t)c2 * N_OUTC + 2 * lane);
            uint_t g3 = *(const uint_t*)(h16 + (size_t)c3 * N_OUTC + 2 * lane);
            uint_t g4 = *(const uint_t*)(h16 + (size_t)c4 * N_OUTC + 2 * lane);
            uint_t g5 = *(const uint_t*)(h16 + (size_t)c5 * N_OUTC + 2 * lane);
            uint_t g6 = *(const uint_t*)(h16 + (size_t)c6 * N_OUTC + 2 * lane);
            uint_t g7 = *(const uint_t*)(h16 + (size_t)c7 * N_OUTC + 2 * lane);
            float v0 = __int_as_float(__shfl(my.y, j + 0));
            float v1 = __int_as_float(__shfl(my.y, j + 1));
            float v2 = __int_as_float(__shfl(my.y, j + 2));
            float v3 = __int_as_float(__shfl(my.y, j + 3));
            float v4 = __int_as_float(__shfl(my.y, j + 4));
            float v5 = __int_as_float(__shfl(my.y, j + 5));
            float v6 = __int_as_float(__shfl(my.y, j + 6));
            float v7 = __int_as_float(__shfl(my.y, j + 7));
            acc.x += v0 * bf_lo(g0); acc.y += v0 * bf_hi(g0);
            acc.x += v1 * bf_lo(g1); acc.y += v1 * bf_hi(g1);
            acc.x += v2 * bf_lo(g2); acc.y += v2 * bf_hi(g2);
            acc.x += v3 * bf_lo(g3); acc.y += v3 * bf_hi(g3);
            acc.x += v4 * bf_lo(g4); acc.y += v4 * bf_hi(g4);
            acc.x += v5 * bf_lo(g5); acc.y += v5 * bf_hi(g5);
            acc.x += v6 * bf_lo(g6); acc.y += v6 * bf_hi(g6);
            acc.x += v7 * bf_lo(g7); acc.y += v7 * bf_hi(g7);
        }
    }

    int p = prev[r];
    uint_t g = *(const uint_t*)(h16 + (size_t)p * N_OUTC + 2 * lane);
    float2* o = (float2*)(out + (size_t)r * 256);
    o[lane]      = make_float2(bf_lo(g), bf_hi(g));
    o[64 + lane] = make_float2(acc.x, acc.y);
}

// ---------------- spill fixup (expected empty) ----------------
__global__ void spill_kernel(const ushort_t* __restrict__ h16, const int4* __restrict__ spill,
                             const int* __restrict__ spillCnt, float* __restrict__ out) {
    int n = *spillCnt; if (n > SPILL_CAP) n = SPILL_CAP;
    int total = n * 64;
    for (int t = blockIdx.x * blockDim.x + threadIdx.x; t < total; t += gridDim.x * blockDim.x) {
        int idx = t >> 6, lane = t & 63;
        int4 s = spill[idx];
        uint_t g = *(const uint_t*)(h16 + (size_t)s.y * N_OUTC + 2 * lane);
        float v = __int_as_float(s.z);
        atomicAdd(&out[(size_t)s.x * 256 + 128 + 2 * lane],     v * bf_lo(g));
        atomicAdd(&out[(size_t)s.x * 256 + 128 + 2 * lane + 1], v * bf_hi(g));
    }
}

// ---------------- fallback path (ws too small; not expected) ----------------
__global__ void concat_only_kernel(const ushort_t* __restrict__ h16, const int* __restrict__ prev,
                                   float* __restrict__ out, int Ndst) {
    int t = blockIdx.x * blockDim.x + threadIdx.x;
    int r = t >> 6, lane = t & 63;
    if (r >= Ndst) return;
    uint_t g = *(const uint_t*)(h16 + (size_t)prev[r] * N_OUTC + 2 * lane);
    ((float2*)out)[(size_t)r * 128 + lane] = make_float2(bf_lo(g), bf_hi(g));
}

__global__ void spmm_atomic_kernel(const ushort_t* __restrict__ h16, const int* __restrict__ rows,
                                   const int* __restrict__ cols, const float* __restrict__ vals,
                                   int E, float* __restrict__ out) {
    long long t = (long long)blockIdx.x * blockDim.x + threadIdx.x;
    int e = (int)(t >> 6), lane = (int)(t & 63);
    if (e >= E) return;
    uint_t g = *(const uint_t*)(h16 + (size_t)cols[e] * N_OUTC + 2 * lane);
    float v = vals[e];
    int r = rows[e];
    atomicAdd(&out[(size_t)r * 256 + 128 + 2 * lane],     v * bf_lo(g));
    atomicAdd(&out[(size_t)r * 256 + 128 + 2 * lane + 1], v * bf_hi(g));
}

extern "C" void kernel_launch(void* const* d_in, const int* in_sizes, int n_in,
                              void* d_out, int out_size, void* d_ws, size_t ws_size,
                              hipStream_t stream) {
    const float* x    = (const float*)d_in[0];
    const float* W    = (const float*)d_in[1];
    const float* b    = (const float*)d_in[2];
    const float* vals = (const float*)d_in[3];
    const int*   rows = (const int*)d_in[4];
    const int*   cols = (const int*)d_in[5];
    const int*   prev = (const int*)d_in[6];
    float* out = (float*)d_out;

    const int Nsrc = in_sizes[0] / N_IN;   // 100000
    const int E    = in_sizes[3];          // 3200000
    const int Ndst = in_sizes[6];          // 50000
    const int NSB  = (Ndst + RPS - 1) / RPS;           // 782
    const int sbCap = E / NSB + 516;                   // mean ~4092 + 8 sigma
    const int nbBuild = (E + TILE - 1) / TILE;         // 782
    const int gemmBlocks = Nsrc / 16;                  // 6250

    char* ws = (char*)d_ws;
    size_t off = 0;
    ushort_t* h16 = (ushort_t*)(ws + off);
    off += (size_t)Nsrc * N_OUTC * sizeof(ushort_t);               // 25.6 MB
    ushort_t* wb = (ushort_t*)(ws + off);
    off += (size_t)N_OUTC * N_IN * sizeof(ushort_t);               // 64 KB
    off = (off + 255) & ~(size_t)255;
    int* sbCount  = (int*)(ws + off);                               // memset zone: NSB + 1
    int* spillCnt = sbCount + NSB;
    size_t memsetBytes = ((size_t)NSB + 1) * sizeof(int);
    off += memsetBytes;
    off = (off + 255) & ~(size_t)255;
    int* sbBase = (int*)(ws + off);
    off += (size_t)NSB * sizeof(int);
    off = (off + 255) & ~(size_t)255;
    int* rowStart = (int*)(ws + off);
    off += (size_t)Ndst * sizeof(int);
    int* rowCnt = (int*)(ws + off);
    off += (size_t)Ndst * sizeof(int);
    off = (off + 255) & ~(size_t)255;
    int4* spill = (int4*)(ws + off);
    off += (size_t)SPILL_CAP * sizeof(int4);
    off = (off + 255) & ~(size_t)255;
    int2* sbList = (int2*)(ws + off);
    off += (size_t)NSB * sbCap * sizeof(int2);                     // ~28.8 MB
    off = (off + 255) & ~(size_t)255;
    int2* csr = (int2*)(ws + off);
    off += (size_t)E * sizeof(int2);                               // 25.6 MB

    cvtW_kernel<<<(N_OUTC * N_IN + 255) / 256, 256, 0, stream>>>(W, wb, N_OUTC * N_IN);

    if (off <= ws_size && NSB <= NSB_MAX) {
        hipMemsetAsync(sbCount, 0, memsetBytes, stream);
        build_kernel<<<nbBuild, 256, 0, stream>>>(rows, cols, vals, E,
                                                  sbCount, sbList, sbCap, NSB, spillCnt, spill);
        gemm_only_kernel<<<gemmBlocks, 256, 0, stream>>>(x, wb, b, h16);
        sbscan_kernel<<<1, 1024, 0, stream>>>(sbCount, sbCap, sbBase, NSB);
        sort_kernel<<<NSB, 1024, 0, stream>>>(sbCount, sbBase, sbList, sbCap,
                                              csr, rowStart, rowCnt, Ndst);
        spmm_concat_kernel<<<(Ndst + 3) / 4, 256, 0, stream>>>(h16, rowStart, rowCnt, csr,
                                                               prev, out, Ndst);
        spill_kernel<<<64, 256, 0, stream>>>(h16, spill, spillCnt, out);
    } else {
        gemm_only_kernel<<<gemmBlocks, 256, 0, stream>>>(x, wb, b, h16);
        hipMemsetAsync(out, 0, (size_t)out_size * sizeof(float), stream);
        concat_only_kernel<<<((size_t)Ndst * 64 + 255) / 256, 256, 0, stream>>>(h16, prev, out, Ndst);
        spmm_atomic_kernel<<<((size_t)E * 64 + 255) / 256, 256, 0, stream>>>(h16, rows, cols, vals, E, out);
    }
}